// Round 1
// baseline (479.462 us; speedup 1.0000x reference)
//
#include <hip/hip_runtime.h>

typedef unsigned short ushort_t;
typedef unsigned int uint32;
typedef __attribute__((ext_vector_type(8))) short short8;
typedef __attribute__((ext_vector_type(4))) float f32x4;

#define LDS_LOAD16(gptr, lptr)                                                             \
  __builtin_amdgcn_global_load_lds((const __attribute__((address_space(1))) uint32*)(gptr),\
                                   (__attribute__((address_space(3))) uint32*)(lptr),      \
                                   16, 0, 0)

__device__ __forceinline__ ushort_t f2b(float f) {
  uint32 u = __builtin_bit_cast(uint32, f);
  u += 0x7fffu + ((u >> 16) & 1u);   // RNE; inputs are normal floats
  return (ushort_t)(u >> 16);
}
__device__ __forceinline__ float b2f(ushort_t b) {
  uint32 u = ((uint32)b) << 16;
  return __builtin_bit_cast(float, u);
}

// ---------------- fp32 -> bf16 convert (4 elems / thread) ----------------
__global__ __launch_bounds__(256) void k_f32_to_bf16(const float* __restrict__ in,
                                                     ushort_t* __restrict__ out) {
  size_t i = ((size_t)blockIdx.x * 256 + threadIdx.x) * 4;
  float4 v = *(const float4*)(in + i);
  ushort4 o;
  o.x = f2b(v.x); o.y = f2b(v.y); o.z = f2b(v.z); o.w = f2b(v.w);
  *(ushort4*)(out + i) = o;
}

// ---------------- bf16 GEMM-BT: C[M,N] = A[M,K] * B[N,K]^T ----------------
// 128x128 tile, BK=32, 256 thr = 4 waves (2x2), each wave 64x64 (4x4 MFMA 16x16x32)
template <bool BF16_OUT>
__global__ __launch_bounds__(256) void k_gemm_bt(const ushort_t* __restrict__ A,
                                                 const ushort_t* __restrict__ B,
                                                 void* __restrict__ Cv,
                                                 int M, int N, int K) {
  __shared__ ushort_t As[128 * 32];
  __shared__ ushort_t Bs[128 * 32];
  const int tid = threadIdx.x;
  const int lane = tid & 63, wave = tid >> 6;
  const int quad = lane >> 4, l16 = lane & 15;
  const int wm = wave >> 1, wn = wave & 1;
  const size_t row0 = (size_t)blockIdx.y * 128, col0 = (size_t)blockIdx.x * 128;

  f32x4 zero = {0.f, 0.f, 0.f, 0.f};
  f32x4 acc[4][4];
#pragma unroll
  for (int i = 0; i < 4; ++i)
#pragma unroll
    for (int j = 0; j < 4; ++j) acc[i][j] = zero;

  const int nkt = K >> 5;
  for (int kt = 0; kt < nkt; ++kt) {
#pragma unroll
    for (int j = 0; j < 2; ++j) {
      int c = tid + 256 * j;  // 512 chunks of 8 bf16; row = c>>2, koff = (c&3)*8
      LDS_LOAD16(A + (row0 + (c >> 2)) * K + kt * 32 + (c & 3) * 8, &As[c * 8]);
      LDS_LOAD16(B + (col0 + (c >> 2)) * K + kt * 32 + (c & 3) * 8, &Bs[c * 8]);
    }
    __syncthreads();
    short8 a[4], b[4];
#pragma unroll
    for (int i = 0; i < 4; ++i) {
      a[i] = *(const short8*)&As[(wm * 64 + i * 16 + l16) * 32 + quad * 8];
      b[i] = *(const short8*)&Bs[(wn * 64 + i * 16 + l16) * 32 + quad * 8];
    }
#pragma unroll
    for (int i = 0; i < 4; ++i)
#pragma unroll
      for (int j = 0; j < 4; ++j)
        acc[i][j] = __builtin_amdgcn_mfma_f32_16x16x32_bf16(a[i], b[j], acc[i][j], 0, 0, 0);
    __syncthreads();
  }

#pragma unroll
  for (int i = 0; i < 4; ++i)
#pragma unroll
    for (int j = 0; j < 4; ++j)
#pragma unroll
      for (int r = 0; r < 4; ++r) {
        size_t row = row0 + wm * 64 + i * 16 + quad * 4 + r;
        size_t col = col0 + wn * 64 + j * 16 + l16;
        if (BF16_OUT)
          ((ushort_t*)Cv)[row * N + col] = f2b(acc[i][j][r]);
        else
          ((float*)Cv)[row * N + col] = acc[i][j][r];
      }
}

// ---------------- RoPE (in-place on Q and K, bf16) ----------------
__global__ __launch_bounds__(256) void k_rope(ushort_t* __restrict__ Q,
                                              ushort_t* __restrict__ Kk,
                                              const int* __restrict__ pos) {
  int idx = blockIdx.x * 256 + threadIdx.x;  // 2048*16*64 pairs
  int f = idx & 63;
  int h = (idx >> 6) & 15;
  int t = idx >> 10;
  float tp = (float)pos[t];
  // inv_freq = 10000^(-f/64) = exp(-f * ln(10000)/64)
  float ang = tp * expf(-0.14391156831212787f * (float)f);
  float sn, cs;
  sincosf(ang, &sn, &cs);
  size_t base = (size_t)t * 2048 + h * 128 + f;
  float q0 = b2f(Q[base]), q1 = b2f(Q[base + 64]);
  Q[base]      = f2b(q0 * cs - q1 * sn);
  Q[base + 64] = f2b(q1 * cs + q0 * sn);
  float k0 = b2f(Kk[base]), k1 = b2f(Kk[base + 64]);
  Kk[base]      = f2b(k0 * cs - k1 * sn);
  Kk[base + 64] = f2b(k1 * cs + k0 * sn);
}

// ---------------- bf16 2048x2048 transpose (V -> V^T) ----------------
__global__ __launch_bounds__(256) void k_transpose(const ushort_t* __restrict__ V,
                                                   ushort_t* __restrict__ Vt) {
  __shared__ ushort_t tile[64][72];  // 144B row stride, 16B-aligned
  const int tid = threadIdx.x;
  const size_t t0 = (size_t)blockIdx.x * 64, d0 = (size_t)blockIdx.y * 64;
#pragma unroll
  for (int j = 0; j < 2; ++j) {
    int c = tid + 256 * j;           // 512 chunks of 8
    int r = c >> 3, cc = (c & 7) * 8;
    *(short8*)&tile[r][cc] = *(const short8*)&V[(t0 + r) * 2048 + d0 + cc];
  }
  __syncthreads();
#pragma unroll
  for (int j = 0; j < 2; ++j) {
    int c = tid + 256 * j;
    int dr = c >> 3, tc = (c & 7) * 8;
    short8 v;
#pragma unroll
    for (int k = 0; k < 8; ++k) ((ushort_t*)&v)[k] = tile[tc + k][dr];
    *(short8*)&Vt[(d0 + dr) * 2048 + t0 + tc] = v;
  }
}

// ---------------- flash attention, non-causal, dh=128, S=2048 ----------------
// grid: (32 q-tiles of 64 rows, 16 heads); 4 waves, each wave owns 16 q rows.
__global__ __launch_bounds__(256) void k_attn(const ushort_t* __restrict__ Q,
                                              const ushort_t* __restrict__ Kg,
                                              const ushort_t* __restrict__ Vt,
                                              ushort_t* __restrict__ O) {
  __shared__ ushort_t Ks[32 * 128];    // [key][dh]
  __shared__ ushort_t Vs[128 * 32];    // [dh][key]  (from V^T)
  __shared__ ushort_t Ps[4][16 * 32];  // per-wave P tile [qrow][key]
  const int tid = threadIdx.x;
  const int lane = tid & 63, wave = tid >> 6;
  const int quad = lane >> 4, l16 = lane & 15;
  const int hh = blockIdx.y;
  const int q0 = blockIdx.x * 64 + wave * 16;

  short8 qf[4];
#pragma unroll
  for (int kk = 0; kk < 4; ++kk)
    qf[kk] = *(const short8*)&Q[(size_t)(q0 + l16) * 2048 + hh * 128 + kk * 32 + quad * 8];

  float m_r[4] = {-3.0e38f, -3.0e38f, -3.0e38f, -3.0e38f};
  float l_r[4] = {0.f, 0.f, 0.f, 0.f};
  f32x4 zero = {0.f, 0.f, 0.f, 0.f};
  f32x4 oacc[8];
#pragma unroll
  for (int ns = 0; ns < 8; ++ns) oacc[ns] = zero;

  const float scale = 0.08838834764831845f;  // 1/sqrt(128)

  for (int kt = 0; kt < 64; ++kt) {
#pragma unroll
    for (int j = 0; j < 2; ++j) {
      int c = tid + 256 * j;
      // K tile: 32 keys x 128 dh (16 chunks/row)
      LDS_LOAD16(Kg + (size_t)(kt * 32 + (c >> 4)) * 2048 + hh * 128 + (c & 15) * 8, &Ks[c * 8]);
      // V^T tile: 128 dh x 32 keys (4 chunks/row)
      LDS_LOAD16(Vt + (size_t)(hh * 128 + (c >> 2)) * 2048 + kt * 32 + (c & 3) * 8, &Vs[c * 8]);
    }
    __syncthreads();

    f32x4 sc[2];
    sc[0] = zero; sc[1] = zero;
#pragma unroll
    for (int kk = 0; kk < 4; ++kk)
#pragma unroll
      for (int ns = 0; ns < 2; ++ns) {
        short8 kf = *(const short8*)&Ks[(ns * 16 + l16) * 128 + kk * 32 + quad * 8];
        sc[ns] = __builtin_amdgcn_mfma_f32_16x16x32_bf16(qf[kk], kf, sc[ns], 0, 0, 0);
      }

    float alpha[4];
#pragma unroll
    for (int r = 0; r < 4; ++r) {
      float s0 = sc[0][r] * scale, s1 = sc[1][r] * scale;
      float mx = fmaxf(s0, s1);
      mx = fmaxf(mx, __shfl_xor(mx, 1, 16));
      mx = fmaxf(mx, __shfl_xor(mx, 2, 16));
      mx = fmaxf(mx, __shfl_xor(mx, 4, 16));
      mx = fmaxf(mx, __shfl_xor(mx, 8, 16));
      float m_new = fmaxf(m_r[r], mx);
      alpha[r] = __expf(m_r[r] - m_new);
      float p0 = __expf(s0 - m_new);
      float p1 = __expf(s1 - m_new);
      float rs = p0 + p1;
      rs += __shfl_xor(rs, 1, 16);
      rs += __shfl_xor(rs, 2, 16);
      rs += __shfl_xor(rs, 4, 16);
      rs += __shfl_xor(rs, 8, 16);
      l_r[r] = l_r[r] * alpha[r] + rs;
      m_r[r] = m_new;
      Ps[wave][(quad * 4 + r) * 32 + l16] = f2b(p0);
      Ps[wave][(quad * 4 + r) * 32 + 16 + l16] = f2b(p1);
    }
#pragma unroll
    for (int ns = 0; ns < 8; ++ns)
#pragma unroll
      for (int r = 0; r < 4; ++r) oacc[ns][r] *= alpha[r];
    __syncthreads();  // P LDS round-trip (C-layout -> A-layout)

    short8 pf = *(const short8*)&Ps[wave][l16 * 32 + quad * 8];
#pragma unroll
    for (int ns = 0; ns < 8; ++ns) {
      short8 vf = *(const short8*)&Vs[(ns * 16 + l16) * 32 + quad * 8];
      oacc[ns] = __builtin_amdgcn_mfma_f32_16x16x32_bf16(pf, vf, oacc[ns], 0, 0, 0);
    }
    __syncthreads();  // protect Ks/Vs before next staging
  }

#pragma unroll
  for (int r = 0; r < 4; ++r) {
    float inv = 1.0f / l_r[r];
#pragma unroll
    for (int ns = 0; ns < 8; ++ns)
      O[(size_t)(q0 + quad * 4 + r) * 2048 + hh * 128 + ns * 16 + l16] = f2b(oacc[ns][r] * inv);
  }
}

extern "C" void kernel_launch(void* const* d_in, const int* in_sizes, int n_in,
                              void* d_out, int out_size, void* d_ws, size_t ws_size,
                              hipStream_t stream) {
  const float* X  = (const float*)d_in[0];
  const float* wq = (const float*)d_in[1];
  const float* wk = (const float*)d_in[2];
  const float* wv = (const float*)d_in[3];
  const float* wo = (const float*)d_in[4];
  const int*  pos = (const int*)d_in[5];
  float* out = (float*)d_out;

  constexpr size_t E = (size_t)2048 * 2048;
  if (ws_size < 10 * E * sizeof(ushort_t)) return;  // need 80 MB scratch

  ushort_t* Xb  = (ushort_t*)d_ws;
  ushort_t* Wqb = Xb + E;
  ushort_t* Wkb = Xb + 2 * E;
  ushort_t* Wvb = Xb + 3 * E;
  ushort_t* Wob = Xb + 4 * E;
  ushort_t* Qm  = Xb + 5 * E;
  ushort_t* Km  = Xb + 6 * E;
  ushort_t* Vm  = Xb + 7 * E;
  ushort_t* Vtm = Xb + 8 * E;
  ushort_t* Om  = Xb + 9 * E;

  dim3 b256(256);
  k_f32_to_bf16<<<4096, b256, 0, stream>>>(X, Xb);
  k_f32_to_bf16<<<4096, b256, 0, stream>>>(wq, Wqb);
  k_f32_to_bf16<<<4096, b256, 0, stream>>>(wk, Wkb);
  k_f32_to_bf16<<<4096, b256, 0, stream>>>(wv, Wvb);
  k_f32_to_bf16<<<4096, b256, 0, stream>>>(wo, Wob);

  dim3 gg(16, 16);
  k_gemm_bt<true><<<gg, b256, 0, stream>>>(Xb, Wqb, Qm, 2048, 2048, 2048);
  k_gemm_bt<true><<<gg, b256, 0, stream>>>(Xb, Wkb, Km, 2048, 2048, 2048);
  k_gemm_bt<true><<<gg, b256, 0, stream>>>(Xb, Wvb, Vm, 2048, 2048, 2048);

  k_rope<<<8192, b256, 0, stream>>>(Qm, Km, pos);
  k_transpose<<<dim3(32, 32), b256, 0, stream>>>(Vm, Vtm);
  k_attn<<<dim3(32, 16), b256, 0, stream>>>(Qm, Km, Vtm, Om);

  k_gemm_bt<false><<<gg, b256, 0, stream>>>(Om, Wob, out, 2048, 2048, 2048);
}

// Round 2
// 332.006 us; speedup vs baseline: 1.4441x; 1.4441x over previous
//
#include <hip/hip_runtime.h>

typedef unsigned short ushort_t;
typedef unsigned int uint32;
typedef __attribute__((ext_vector_type(8))) short short8;
typedef __attribute__((ext_vector_type(4))) float f32x4;

#define LDS_LOAD16(gptr, lptr)                                                             \
  __builtin_amdgcn_global_load_lds((const __attribute__((address_space(1))) uint32*)(gptr),\
                                   (__attribute__((address_space(3))) uint32*)(lptr),      \
                                   16, 0, 0)

__device__ __forceinline__ ushort_t f2b(float f) {
  uint32 u = __builtin_bit_cast(uint32, f);
  u += 0x7fffu + ((u >> 16) & 1u);   // RNE
  return (ushort_t)(u >> 16);
}
__device__ __forceinline__ float b2f(ushort_t b) {
  uint32 u = ((uint32)b) << 16;
  return __builtin_bit_cast(float, u);
}
__device__ __forceinline__ int swz4(int row) { return (row ^ (row >> 2)) & 3; }

constexpr size_t E = (size_t)2048 * 2048;

// ---------------- fused fp32 -> bf16 convert (all 5 tensors) ----------------
__global__ __launch_bounds__(256) void k_cvt5(const float* __restrict__ a0, const float* __restrict__ a1,
                                              const float* __restrict__ a2, const float* __restrict__ a3,
                                              const float* __restrict__ a4, ushort_t* __restrict__ out) {
  const float* srcs[5] = {a0, a1, a2, a3, a4};
  const float* s = srcs[blockIdx.y];
  size_t i = ((size_t)blockIdx.x * 256 + threadIdx.x) * 4;
  float4 v = *(const float4*)(s + i);
  ushort4 o;
  o.x = f2b(v.x); o.y = f2b(v.y); o.z = f2b(v.z); o.w = f2b(v.w);
  *(ushort4*)(out + (size_t)blockIdx.y * E + i) = o;
}

// ---------------- fused QKV GEMM-BT: 128x128 tile, swizzled LDS ----------------
// z=0 -> Qm (row-major), z=1 -> Km (row-major), z=2 -> Vt (transposed write)
__global__ __launch_bounds__(256) void k_gemm_qkv(const ushort_t* __restrict__ A,
                                                  const ushort_t* __restrict__ B0,
                                                  const ushort_t* __restrict__ B1,
                                                  const ushort_t* __restrict__ B2,
                                                  ushort_t* __restrict__ Qm,
                                                  ushort_t* __restrict__ Km,
                                                  ushort_t* __restrict__ Vt) {
  __shared__ ushort_t As[128 * 32];
  __shared__ ushort_t Bs[128 * 32];
  const int tid = threadIdx.x;
  const int lane = tid & 63, wave = tid >> 6;
  const int quad = lane >> 4, l16 = lane & 15;
  const int wm = wave >> 1, wn = wave & 1;
  const int z = blockIdx.z;
  const ushort_t* Bp = (z == 0) ? B0 : (z == 1) ? B1 : B2;
  const size_t row0 = (size_t)blockIdx.y * 128, col0 = (size_t)blockIdx.x * 128;
  const int sw = swz4(l16);

  f32x4 zero = {0.f, 0.f, 0.f, 0.f};
  f32x4 acc[4][4];
#pragma unroll
  for (int i = 0; i < 4; ++i)
#pragma unroll
    for (int j = 0; j < 4; ++j) acc[i][j] = zero;

  for (int kt = 0; kt < 64; ++kt) {
#pragma unroll
    for (int j = 0; j < 2; ++j) {
      int c = tid + 256 * j;
      int r = c >> 2, p = c & 3;
      int srcc = (p ^ swz4(r)) * 8;
      LDS_LOAD16(A + (row0 + r) * 2048 + kt * 32 + srcc, &As[c * 8]);
      LDS_LOAD16(Bp + (col0 + r) * 2048 + kt * 32 + srcc, &Bs[c * 8]);
    }
    __syncthreads();
    short8 a[4], b[4];
#pragma unroll
    for (int i = 0; i < 4; ++i) {
      int ra = wm * 64 + i * 16 + l16;
      int rb = wn * 64 + i * 16 + l16;
      a[i] = *(const short8*)&As[(ra * 4 + (quad ^ sw)) * 8];
      b[i] = *(const short8*)&Bs[(rb * 4 + (quad ^ sw)) * 8];
    }
#pragma unroll
    for (int i = 0; i < 4; ++i)
#pragma unroll
      for (int j = 0; j < 4; ++j)
        acc[i][j] = __builtin_amdgcn_mfma_f32_16x16x32_bf16(a[i], b[j], acc[i][j], 0, 0, 0);
    __syncthreads();
  }

  if (z < 2) {
    ushort_t* C = z ? Km : Qm;
#pragma unroll
    for (int i = 0; i < 4; ++i)
#pragma unroll
      for (int j = 0; j < 4; ++j)
#pragma unroll
        for (int r = 0; r < 4; ++r) {
          size_t row = row0 + wm * 64 + i * 16 + quad * 4 + r;
          size_t col = col0 + wn * 64 + j * 16 + l16;
          C[row * 2048 + col] = f2b(acc[i][j][r]);
        }
  } else {
#pragma unroll
    for (int i = 0; i < 4; ++i)
#pragma unroll
      for (int j = 0; j < 4; ++j) {
        size_t col = col0 + wn * 64 + j * 16 + l16;
        size_t rowb = row0 + wm * 64 + i * 16 + quad * 4;
        ushort4 ov;
        ov.x = f2b(acc[i][j][0]); ov.y = f2b(acc[i][j][1]);
        ov.z = f2b(acc[i][j][2]); ov.w = f2b(acc[i][j][3]);
        *(ushort4*)&Vt[col * 2048 + rowb] = ov;
      }
  }
}

// ---------------- RoPE (in-place on Q and K, bf16) ----------------
__global__ __launch_bounds__(256) void k_rope(ushort_t* __restrict__ Q,
                                              ushort_t* __restrict__ Kk,
                                              const int* __restrict__ pos) {
  int idx = blockIdx.x * 256 + threadIdx.x;  // 2048*16*64 pairs
  int f = idx & 63;
  int h = (idx >> 6) & 15;
  int t = idx >> 10;
  float tp = (float)pos[t];
  float ang = tp * expf(-0.14391156831212787f * (float)f);
  float sn, cs;
  sincosf(ang, &sn, &cs);
  size_t base = (size_t)t * 2048 + h * 128 + f;
  float q0 = b2f(Q[base]), q1 = b2f(Q[base + 64]);
  Q[base]      = f2b(q0 * cs - q1 * sn);
  Q[base + 64] = f2b(q1 * cs + q0 * sn);
  float k0 = b2f(Kk[base]), k1 = b2f(Kk[base + 64]);
  Kk[base]      = f2b(k0 * cs - k1 * sn);
  Kk[base + 64] = f2b(k1 * cs + k0 * sn);
}

// ---------------- flash attention v2: key-split waves, no K/V LDS, no loop barriers ----------------
// grid 512 blocks: 64 q-rows x 16 heads, XCD-clustered (2 heads per XCD slot).
// Each wave owns a disjoint key slice; cross-wave O/l reduction at the end.
__global__ __launch_bounds__(256, 2) void k_attn(const ushort_t* __restrict__ Q,
                                                 const ushort_t* __restrict__ Kg,
                                                 const ushort_t* __restrict__ Vt,
                                                 ushort_t* __restrict__ O) {
  __shared__ ushort_t Qs[64 * 128];      // swizzled: row r, chunk c stored at c ^ (r&15)
  __shared__ float Rbuf[4][16][132];
  __shared__ float Lred[4][4][16];
  const int tid = threadIdx.x;
  const int lane = tid & 63, wave = tid >> 6;
  const int quad = lane >> 4, l16 = lane & 15;
  const int bid = blockIdx.x;
  const int head = ((bid & 7) << 1) + ((bid >> 3) >> 5);
  const int qt = (bid >> 3) & 31;

  // one-time Q staging (64 rows x 128 dh), swizzled
#pragma unroll
  for (int j = 0; j < 4; ++j) {
    int s = tid + 256 * j;
    int r = s >> 4, p = s & 15;
    LDS_LOAD16(Q + (size_t)(qt * 64 + r) * 2048 + head * 128 + ((p ^ (r & 15)) * 8), &Qs[s * 8]);
  }
  __syncthreads();

  f32x4 zero = {0.f, 0.f, 0.f, 0.f};
  f32x4 oacc[4][8];
#pragma unroll
  for (int qg = 0; qg < 4; ++qg)
#pragma unroll
    for (int ns = 0; ns < 8; ++ns) oacc[qg][ns] = zero;
  float l_acc[4] = {0.f, 0.f, 0.f, 0.f};
  const float scale = 0.08838834764831845f;  // 1/sqrt(128)
  const int srcA = ((quad & 1) << 5) | l16;
  const int srcB = srcA + 16;
  const bool hiq = quad >= 2;

  const ushort_t* Kbase = Kg + (size_t)head * 128;
  const ushort_t* Vbase = Vt + (size_t)head * 128 * 2048;

  for (int it = 0; it < 16; ++it) {
    const int kb = it * 128 + wave * 32;  // this wave's 32 keys this iteration

    short8 kf[2][4];
#pragma unroll
    for (int kg = 0; kg < 2; ++kg)
#pragma unroll
      for (int kk = 0; kk < 4; ++kk)
        kf[kg][kk] = *(const short8*)&Kbase[(size_t)(kb + kg * 16 + l16) * 2048 + kk * 32 + quad * 8];

    uint32 pp[4][2][2];
#pragma unroll
    for (int qg = 0; qg < 4; ++qg) {
      short8 qa[4];
#pragma unroll
      for (int kk = 0; kk < 4; ++kk)
        qa[kk] = *(const short8*)&Qs[((qg * 16 + l16) * 16 + ((kk * 4 + quad) ^ l16)) * 8];
      f32x4 s0 = zero, s1 = zero;
#pragma unroll
      for (int kk = 0; kk < 4; ++kk) {
        s0 = __builtin_amdgcn_mfma_f32_16x16x32_bf16(kf[0][kk], qa[kk], s0, 0, 0, 0);
        s1 = __builtin_amdgcn_mfma_f32_16x16x32_bf16(kf[1][kk], qa[kk], s1, 0, 0, 0);
      }
      float p00 = __expf(s0[0] * scale), p01 = __expf(s0[1] * scale);
      float p02 = __expf(s0[2] * scale), p03 = __expf(s0[3] * scale);
      float p10 = __expf(s1[0] * scale), p11 = __expf(s1[1] * scale);
      float p12 = __expf(s1[2] * scale), p13 = __expf(s1[3] * scale);
      l_acc[qg] += ((p00 + p01) + (p02 + p03)) + ((p10 + p11) + (p12 + p13));
      pp[qg][0][0] = (uint32)f2b(p00) | ((uint32)f2b(p01) << 16);
      pp[qg][0][1] = (uint32)f2b(p02) | ((uint32)f2b(p03) << 16);
      pp[qg][1][0] = (uint32)f2b(p10) | ((uint32)f2b(p11) << 16);
      pp[qg][1][1] = (uint32)f2b(p12) | ((uint32)f2b(p13) << 16);
    }

    // P^T (C-layout) -> B-operand layout: quad-permutation shuffles, l16 preserved
    short8 pb[4];
#pragma unroll
    for (int qg = 0; qg < 4; ++qg) {
      uint32 a0 = (uint32)__shfl((int)pp[qg][0][0], srcA, 64);
      uint32 b0 = (uint32)__shfl((int)pp[qg][1][0], srcA, 64);
      uint32 a1 = (uint32)__shfl((int)pp[qg][0][1], srcA, 64);
      uint32 b1 = (uint32)__shfl((int)pp[qg][1][1], srcA, 64);
      uint32 a2 = (uint32)__shfl((int)pp[qg][0][0], srcB, 64);
      uint32 b2 = (uint32)__shfl((int)pp[qg][1][0], srcB, 64);
      uint32 a3 = (uint32)__shfl((int)pp[qg][0][1], srcB, 64);
      uint32 b3 = (uint32)__shfl((int)pp[qg][1][1], srcB, 64);
      union { uint32 u[4]; short8 v; } cvt;
      cvt.u[0] = hiq ? b0 : a0;
      cvt.u[1] = hiq ? b1 : a1;
      cvt.u[2] = hiq ? b2 : a2;
      cvt.u[3] = hiq ? b3 : a3;
      pb[qg] = cvt.v;
    }

#pragma unroll
    for (int ns = 0; ns < 8; ++ns) {
      const short8 vf = *(const short8*)&Vbase[(size_t)(ns * 16 + l16) * 2048 + kb + quad * 8];
#pragma unroll
      for (int qg = 0; qg < 4; ++qg)
        oacc[qg][ns] = __builtin_amdgcn_mfma_f32_16x16x32_bf16(vf, pb[qg], oacc[qg][ns], 0, 0, 0);
    }
  }

  // cross-quad l reduction (each lane's qrow = l16 per group)
#pragma unroll
  for (int qg = 0; qg < 4; ++qg) {
    float l = l_acc[qg];
    l += __shfl_xor(l, 16, 64);
    l += __shfl_xor(l, 32, 64);
    l_acc[qg] = l;
  }
  if (quad == 0) {
#pragma unroll
    for (int qg = 0; qg < 4; ++qg) Lred[wave][qg][l16] = l_acc[qg];
  }

  // cross-wave O reduction, one 16-qrow group at a time
  const int tq = tid >> 4;
  const int td = (tid & 15) * 8;
  for (int qg = 0; qg < 4; ++qg) {
    __syncthreads();  // Rbuf free (and Lred visible on first pass)
#pragma unroll
    for (int ns = 0; ns < 8; ++ns)
      *(f32x4*)&Rbuf[wave][l16][ns * 16 + quad * 4] = oacc[qg][ns];
    __syncthreads();
    float lt = Lred[0][qg][tq] + Lred[1][qg][tq] + Lred[2][qg][tq] + Lred[3][qg][tq];
    float inv = 1.0f / lt;
    f32x4 sA = zero, sB = zero;
#pragma unroll
    for (int w = 0; w < 4; ++w) {
      sA += *(const f32x4*)&Rbuf[w][tq][td];
      sB += *(const f32x4*)&Rbuf[w][tq][td + 4];
    }
    ushort4 o1, o2;
    o1.x = f2b(sA[0] * inv); o1.y = f2b(sA[1] * inv);
    o1.z = f2b(sA[2] * inv); o1.w = f2b(sA[3] * inv);
    o2.x = f2b(sB[0] * inv); o2.y = f2b(sB[1] * inv);
    o2.z = f2b(sB[2] * inv); o2.w = f2b(sB[3] * inv);
    size_t orow = (size_t)(qt * 64 + qg * 16 + tq) * 2048 + head * 128 + td;
    *(ushort4*)&O[orow] = o1;
    *(ushort4*)&O[orow + 4] = o2;
  }
}

// ---------------- Wo GEMM-BT: 128x64 tile, fp32 output ----------------
__global__ __launch_bounds__(256) void k_gemm_wo(const ushort_t* __restrict__ A,
                                                 const ushort_t* __restrict__ B,
                                                 float* __restrict__ C) {
  __shared__ ushort_t As[128 * 32];
  __shared__ ushort_t Bs[64 * 32];
  const int tid = threadIdx.x;
  const int lane = tid & 63, wave = tid >> 6;
  const int quad = lane >> 4, l16 = lane & 15;
  const int wm = wave >> 1, wn = wave & 1;
  const size_t row0 = (size_t)blockIdx.y * 128, col0 = (size_t)blockIdx.x * 64;
  const int sw = swz4(l16);

  f32x4 zero = {0.f, 0.f, 0.f, 0.f};
  f32x4 acc[4][2];
#pragma unroll
  for (int i = 0; i < 4; ++i)
#pragma unroll
    for (int j = 0; j < 2; ++j) acc[i][j] = zero;

  for (int kt = 0; kt < 64; ++kt) {
#pragma unroll
    for (int j = 0; j < 2; ++j) {
      int c = tid + 256 * j;
      int r = c >> 2, p = c & 3;
      LDS_LOAD16(A + (row0 + r) * 2048 + kt * 32 + (p ^ swz4(r)) * 8, &As[c * 8]);
    }
    {
      int c = tid;
      int r = c >> 2, p = c & 3;
      LDS_LOAD16(B + (col0 + r) * 2048 + kt * 32 + (p ^ swz4(r)) * 8, &Bs[c * 8]);
    }
    __syncthreads();
    short8 a[4], b[2];
#pragma unroll
    for (int i = 0; i < 4; ++i)
      a[i] = *(const short8*)&As[((wm * 64 + i * 16 + l16) * 4 + (quad ^ sw)) * 8];
#pragma unroll
    for (int j = 0; j < 2; ++j)
      b[j] = *(const short8*)&Bs[((wn * 32 + j * 16 + l16) * 4 + (quad ^ sw)) * 8];
#pragma unroll
    for (int i = 0; i < 4; ++i)
#pragma unroll
      for (int j = 0; j < 2; ++j)
        acc[i][j] = __builtin_amdgcn_mfma_f32_16x16x32_bf16(a[i], b[j], acc[i][j], 0, 0, 0);
    __syncthreads();
  }

#pragma unroll
  for (int i = 0; i < 4; ++i)
#pragma unroll
    for (int j = 0; j < 2; ++j)
#pragma unroll
      for (int r = 0; r < 4; ++r) {
        size_t row = row0 + wm * 64 + i * 16 + quad * 4 + r;
        size_t col = col0 + wn * 32 + j * 16 + l16;
        C[row * 2048 + col] = acc[i][j][r];
      }
}

extern "C" void kernel_launch(void* const* d_in, const int* in_sizes, int n_in,
                              void* d_out, int out_size, void* d_ws, size_t ws_size,
                              hipStream_t stream) {
  const float* X  = (const float*)d_in[0];
  const float* wq = (const float*)d_in[1];
  const float* wk = (const float*)d_in[2];
  const float* wv = (const float*)d_in[3];
  const float* wo = (const float*)d_in[4];
  const int*  pos = (const int*)d_in[5];
  float* out = (float*)d_out;

  if (ws_size < 9 * E * sizeof(ushort_t)) return;  // need 72 MB scratch

  ushort_t* Xb  = (ushort_t*)d_ws;
  ushort_t* Wqb = Xb + E;
  ushort_t* Wkb = Xb + 2 * E;
  ushort_t* Wvb = Xb + 3 * E;
  ushort_t* Wob = Xb + 4 * E;
  ushort_t* Qm  = Xb + 5 * E;
  ushort_t* Km  = Xb + 6 * E;
  ushort_t* Vtm = Xb + 7 * E;
  ushort_t* Om  = Xb + 8 * E;

  dim3 b256(256);
  k_cvt5<<<dim3(4096, 5), b256, 0, stream>>>(X, wq, wk, wv, wo, Xb);
  k_gemm_qkv<<<dim3(16, 16, 3), b256, 0, stream>>>(Xb, Wqb, Wkb, Wvb, Qm, Km, Vtm);
  k_rope<<<8192, b256, 0, stream>>>(Qm, Km, pos);
  k_attn<<<512, b256, 0, stream>>>(Qm, Km, Vtm, Om);
  k_gemm_wo<<<dim3(32, 16), b256, 0, stream>>>(Om, Wob, out);
}

// Round 4
// 317.975 us; speedup vs baseline: 1.5079x; 1.0441x over previous
//
#include <hip/hip_runtime.h>

typedef unsigned short ushort_t;
typedef unsigned int uint32;
typedef __attribute__((ext_vector_type(8))) short short8;
typedef __attribute__((ext_vector_type(4))) float f32x4;

#define LDS_LOAD16(gptr, lptr)                                                             \
  __builtin_amdgcn_global_load_lds((const __attribute__((address_space(1))) uint32*)(gptr),\
                                   (__attribute__((address_space(3))) uint32*)(lptr),      \
                                   16, 0, 0)

__device__ __forceinline__ ushort_t f2b(float f) {
  uint32 u = __builtin_bit_cast(uint32, f);
  u += 0x7fffu + ((u >> 16) & 1u);   // RNE
  return (ushort_t)(u >> 16);
}
__device__ __forceinline__ float b2f(ushort_t b) {
  uint32 u = ((uint32)b) << 16;
  return __builtin_bit_cast(float, u);
}
__device__ __forceinline__ uint32 pk2(float a, float b) {
  return (uint32)f2b(a) | ((uint32)f2b(b) << 16);
}
__device__ __forceinline__ int swz8(int r) { return (r ^ (r >> 3)) & 7; }

constexpr size_t E = (size_t)2048 * 2048;

// ---------------- fused fp32 -> bf16 convert (all 5 tensors) ----------------
__global__ __launch_bounds__(256) void k_cvt5(const float* __restrict__ a0, const float* __restrict__ a1,
                                              const float* __restrict__ a2, const float* __restrict__ a3,
                                              const float* __restrict__ a4, ushort_t* __restrict__ out) {
  const float* srcs[5] = {a0, a1, a2, a3, a4};
  const float* s = srcs[blockIdx.y];
  size_t i = ((size_t)blockIdx.x * 256 + threadIdx.x) * 4;
  float4 v = *(const float4*)(s + i);
  ushort4 o;
  o.x = f2b(v.x); o.y = f2b(v.y); o.z = f2b(v.z); o.w = f2b(v.w);
  *(ushort4*)(out + (size_t)blockIdx.y * E + i) = o;
}

// ---------------- fused QKV GEMM-BT, BK=64, fused RoPE epilogue ----------------
// z=0 -> Qm (rope + 1/sqrt(dh) scale), z=1 -> Km (rope), z=2 -> Vt (transposed write)
// Wave col-tiles remapped to {0,1,4,5}/{2,3,6,7} so rope pair (f, f+64) is
// acc[i][j] / acc[i][j+2] in the SAME lane -> in-register rope, no LDS exchange.
__global__ __launch_bounds__(256) void k_gemm_qkv(const ushort_t* __restrict__ A,
                                                  const ushort_t* __restrict__ B0,
                                                  const ushort_t* __restrict__ B1,
                                                  const ushort_t* __restrict__ B2,
                                                  ushort_t* __restrict__ Qm,
                                                  ushort_t* __restrict__ Km,
                                                  ushort_t* __restrict__ Vt,
                                                  const int* __restrict__ pos) {
  __shared__ ushort_t As[128 * 64];
  __shared__ ushort_t Bs[128 * 64];
  const int tid = threadIdx.x;
  const int lane = tid & 63, wave = tid >> 6;
  const int quad = lane >> 4, l16 = lane & 15;
  const int wm = wave >> 1, wn = wave & 1;
  const int z = blockIdx.z;
  const ushort_t* Bp = (z == 0) ? B0 : (z == 1) ? B1 : B2;
  const size_t row0 = (size_t)blockIdx.y * 128, col0 = (size_t)blockIdx.x * 128;

  int g[4];
#pragma unroll
  for (int j = 0; j < 4; ++j) g[j] = (j & 1) + ((j >> 1) << 2) + wn * 2;  // {0,1,4,5}/{2,3,6,7}

  f32x4 zero = {0.f, 0.f, 0.f, 0.f};
  f32x4 acc[4][4];
#pragma unroll
  for (int i = 0; i < 4; ++i)
#pragma unroll
    for (int j = 0; j < 4; ++j) acc[i][j] = zero;

  for (int kt = 0; kt < 32; ++kt) {
#pragma unroll
    for (int j2 = 0; j2 < 4; ++j2) {
      int c = tid + 256 * j2;            // 1024 chunks of 16B per matrix
      int r = c >> 3, p = c & 7;
      int sc = (p ^ swz8(r)) * 8;
      LDS_LOAD16(A + (row0 + r) * 2048 + kt * 64 + sc, &As[c * 8]);
      LDS_LOAD16(Bp + (col0 + r) * 2048 + kt * 64 + sc, &Bs[c * 8]);
    }
    __syncthreads();
    short8 a[4][2], b[4][2];
#pragma unroll
    for (int i = 0; i < 4; ++i) {
      int ra = wm * 64 + i * 16 + l16;
#pragma unroll
      for (int kk = 0; kk < 2; ++kk)
        a[i][kk] = *(const short8*)&As[(ra * 8 + ((kk * 4 + quad) ^ swz8(ra))) * 8];
    }
#pragma unroll
    for (int j = 0; j < 4; ++j) {
      int rb = g[j] * 16 + l16;
#pragma unroll
      for (int kk = 0; kk < 2; ++kk)
        b[j][kk] = *(const short8*)&Bs[(rb * 8 + ((kk * 4 + quad) ^ swz8(rb))) * 8];
    }
#pragma unroll
    for (int kk = 0; kk < 2; ++kk)
#pragma unroll
      for (int i = 0; i < 4; ++i)
#pragma unroll
        for (int j = 0; j < 4; ++j)
          acc[i][j] = __builtin_amdgcn_mfma_f32_16x16x32_bf16(a[i][kk], b[j][kk], acc[i][j], 0, 0, 0);
    __syncthreads();
  }

  if (z < 2) {
    ushort_t* C = z ? Km : Qm;
    const float mul = z ? 1.0f : 0.08838834764831845f;  // fold 1/sqrt(128) into Q
#pragma unroll
    for (int i = 0; i < 4; ++i)
#pragma unroll
      for (int r = 0; r < 4; ++r) {
        size_t row = row0 + wm * 64 + i * 16 + quad * 4 + r;
        float pt = (float)pos[row];
        size_t rowoff = row * 2048 + col0;
#pragma unroll
        for (int j = 0; j < 2; ++j) {
          int f = g[j] * 16 + l16;   // f in [0,64)
          float ang = pt * __expf(-0.14391156831212787f * (float)f);
          float sn, cs;
          __sincosf(ang, &sn, &cs);
          cs *= mul; sn *= mul;
          float q0 = acc[i][j][r], q1 = acc[i][j + 2][r];
          C[rowoff + f]      = f2b(q0 * cs - q1 * sn);
          C[rowoff + f + 64] = f2b(q1 * cs + q0 * sn);
        }
      }
  } else {
#pragma unroll
    for (int i = 0; i < 4; ++i)
#pragma unroll
      for (int j = 0; j < 4; ++j) {
        size_t col = col0 + g[j] * 16 + l16;
        size_t rowb = row0 + wm * 64 + i * 16 + quad * 4;
        ushort4 ov;
        ov.x = f2b(acc[i][j][0]); ov.y = f2b(acc[i][j][1]);
        ov.z = f2b(acc[i][j][2]); ov.w = f2b(acc[i][j][3]);
        *(ushort4*)&Vt[col * 2048 + rowb] = ov;
      }
  }
}

// ---------------- flash attention: key-split waves, no K/V LDS, no loop barriers ----------------
// Q arrives pre-scaled by 1/sqrt(dh). grid 512: 64 q-rows x 16 heads, XCD-clustered.
__global__ __launch_bounds__(256, 2) void k_attn(const ushort_t* __restrict__ Q,
                                                 const ushort_t* __restrict__ Kg,
                                                 const ushort_t* __restrict__ Vt,
                                                 ushort_t* __restrict__ O) {
  __shared__ ushort_t Qs[64 * 128];      // swizzled: row r, chunk c stored at c ^ (r&15)
  __shared__ float Rbuf[4][16][132];
  __shared__ float Lred[4][4][16];
  const int tid = threadIdx.x;
  const int lane = tid & 63, wave = tid >> 6;
  const int quad = lane >> 4, l16 = lane & 15;
  const int bid = blockIdx.x;
  const int head = ((bid & 7) << 1) + ((bid >> 3) >> 5);
  const int qt = (bid >> 3) & 31;

#pragma unroll
  for (int j = 0; j < 4; ++j) {
    int s = tid + 256 * j;
    int r = s >> 4, p = s & 15;
    LDS_LOAD16(Q + (size_t)(qt * 64 + r) * 2048 + head * 128 + ((p ^ (r & 15)) * 8), &Qs[s * 8]);
  }
  __syncthreads();

  f32x4 zero = {0.f, 0.f, 0.f, 0.f};
  f32x4 oacc[4][8];
#pragma unroll
  for (int qg = 0; qg < 4; ++qg)
#pragma unroll
    for (int ns = 0; ns < 8; ++ns) oacc[qg][ns] = zero;
  float l_acc[4] = {0.f, 0.f, 0.f, 0.f};
  const int srcA = ((quad & 1) << 5) | l16;
  const int srcB = srcA + 16;
  const bool hiq = quad >= 2;

  const ushort_t* Kbase = Kg + (size_t)head * 128;
  const ushort_t* Vbase = Vt + (size_t)head * 128 * 2048;

  for (int it = 0; it < 16; ++it) {
    const int kb = it * 128 + wave * 32;

    short8 kf[2][4];
#pragma unroll
    for (int kg = 0; kg < 2; ++kg)
#pragma unroll
      for (int kk = 0; kk < 4; ++kk)
        kf[kg][kk] = *(const short8*)&Kbase[(size_t)(kb + kg * 16 + l16) * 2048 + kk * 32 + quad * 8];

    uint32 pp[4][2][2];
#pragma unroll
    for (int qg = 0; qg < 4; ++qg) {
      short8 qa[4];
#pragma unroll
      for (int kk = 0; kk < 4; ++kk)
        qa[kk] = *(const short8*)&Qs[((qg * 16 + l16) * 16 + ((kk * 4 + quad) ^ l16)) * 8];
      f32x4 s0 = zero, s1 = zero;
#pragma unroll
      for (int kk = 0; kk < 4; ++kk) {
        s0 = __builtin_amdgcn_mfma_f32_16x16x32_bf16(kf[0][kk], qa[kk], s0, 0, 0, 0);
        s1 = __builtin_amdgcn_mfma_f32_16x16x32_bf16(kf[1][kk], qa[kk], s1, 0, 0, 0);
      }
      float p00 = __expf(s0[0]), p01 = __expf(s0[1]);
      float p02 = __expf(s0[2]), p03 = __expf(s0[3]);
      float p10 = __expf(s1[0]), p11 = __expf(s1[1]);
      float p12 = __expf(s1[2]), p13 = __expf(s1[3]);
      l_acc[qg] += ((p00 + p01) + (p02 + p03)) + ((p10 + p11) + (p12 + p13));
      pp[qg][0][0] = pk2(p00, p01);
      pp[qg][0][1] = pk2(p02, p03);
      pp[qg][1][0] = pk2(p10, p11);
      pp[qg][1][1] = pk2(p12, p13);
    }

    short8 pb[4];
#pragma unroll
    for (int qg = 0; qg < 4; ++qg) {
      uint32 a0 = (uint32)__shfl((int)pp[qg][0][0], srcA, 64);
      uint32 b0 = (uint32)__shfl((int)pp[qg][1][0], srcA, 64);
      uint32 a1 = (uint32)__shfl((int)pp[qg][0][1], srcA, 64);
      uint32 b1 = (uint32)__shfl((int)pp[qg][1][1], srcB - 16, 64);
      uint32 a2 = (uint32)__shfl((int)pp[qg][0][0], srcB, 64);
      uint32 b2 = (uint32)__shfl((int)pp[qg][1][0], srcB, 64);
      uint32 a3 = (uint32)__shfl((int)pp[qg][0][1], srcB, 64);
      uint32 b3 = (uint32)__shfl((int)pp[qg][1][1], srcB, 64);
      // NOTE: b1 must come from srcA; fix the accidental srcB-16 (== srcA) alias kept explicit:
      union { uint32 u[4]; short8 v; } cvt;
      cvt.u[0] = hiq ? b0 : a0;
      cvt.u[1] = hiq ? b1 : a1;
      cvt.u[2] = hiq ? b2 : a2;
      cvt.u[3] = hiq ? b3 : a3;
      pb[qg] = cvt.v;
    }

#pragma unroll
    for (int ns = 0; ns < 8; ++ns) {
      const short8 vf = *(const short8*)&Vbase[(size_t)(ns * 16 + l16) * 2048 + kb + quad * 8];
#pragma unroll
      for (int qg = 0; qg < 4; ++qg)
        oacc[qg][ns] = __builtin_amdgcn_mfma_f32_16x16x32_bf16(vf, pb[qg], oacc[qg][ns], 0, 0, 0);
    }
  }

#pragma unroll
  for (int qg = 0; qg < 4; ++qg) {
    float l = l_acc[qg];
    l += __shfl_xor(l, 16, 64);
    l += __shfl_xor(l, 32, 64);
    l_acc[qg] = l;
  }
  if (quad == 0) {
#pragma unroll
    for (int qg = 0; qg < 4; ++qg) Lred[wave][qg][l16] = l_acc[qg];
  }

  const int tq = tid >> 4;
  const int td = (tid & 15) * 8;
  for (int qg = 0; qg < 4; ++qg) {
    __syncthreads();
#pragma unroll
    for (int ns = 0; ns < 8; ++ns)
      *(f32x4*)&Rbuf[wave][l16][ns * 16 + quad * 4] = oacc[qg][ns];
    __syncthreads();
    float lt = Lred[0][qg][tq] + Lred[1][qg][tq] + Lred[2][qg][tq] + Lred[3][qg][tq];
    float inv = 1.0f / lt;
    f32x4 sA = zero, sB = zero;
#pragma unroll
    for (int w = 0; w < 4; ++w) {
      sA += *(const f32x4*)&Rbuf[w][tq][td];
      sB += *(const f32x4*)&Rbuf[w][tq][td + 4];
    }
    ushort4 o1, o2;
    o1.x = f2b(sA[0] * inv); o1.y = f2b(sA[1] * inv);
    o1.z = f2b(sA[2] * inv); o1.w = f2b(sA[3] * inv);
    o2.x = f2b(sB[0] * inv); o2.y = f2b(sB[1] * inv);
    o2.z = f2b(sB[2] * inv); o2.w = f2b(sB[3] * inv);
    size_t orow = (size_t)(qt * 64 + qg * 16 + tq) * 2048 + head * 128 + td;
    *(ushort4*)&O[orow] = o1;
    *(ushort4*)&O[orow + 4] = o2;
  }
}

// ---------------- Wo GEMM-BT: 128x64 tile, BK=64, fp32 output ----------------
__global__ __launch_bounds__(256) void k_gemm_wo(const ushort_t* __restrict__ A,
                                                 const ushort_t* __restrict__ B,
                                                 float* __restrict__ C) {
  __shared__ ushort_t As[128 * 64];
  __shared__ ushort_t Bs[64 * 64];
  const int tid = threadIdx.x;
  const int lane = tid & 63, wave = tid >> 6;
  const int quad = lane >> 4, l16 = lane & 15;
  const int wm = wave >> 1, wn = wave & 1;
  const size_t row0 = (size_t)blockIdx.y * 128, col0 = (size_t)blockIdx.x * 64;

  f32x4 zero = {0.f, 0.f, 0.f, 0.f};
  f32x4 acc[4][2];
#pragma unroll
  for (int i = 0; i < 4; ++i)
#pragma unroll
    for (int j = 0; j < 2; ++j) acc[i][j] = zero;

  for (int kt = 0; kt < 32; ++kt) {
#pragma unroll
    for (int j2 = 0; j2 < 4; ++j2) {
      int c = tid + 256 * j2;
      int r = c >> 3, p = c & 7;
      LDS_LOAD16(A + (row0 + r) * 2048 + kt * 64 + (p ^ swz8(r)) * 8, &As[c * 8]);
    }
#pragma unroll
    for (int j2 = 0; j2 < 2; ++j2) {
      int c = tid + 256 * j2;
      int r = c >> 3, p = c & 7;
      LDS_LOAD16(B + (col0 + r) * 2048 + kt * 64 + (p ^ swz8(r)) * 8, &Bs[c * 8]);
    }
    __syncthreads();
    short8 a[4][2], b[2][2];
#pragma unroll
    for (int i = 0; i < 4; ++i) {
      int ra = wm * 64 + i * 16 + l16;
#pragma unroll
      for (int kk = 0; kk < 2; ++kk)
        a[i][kk] = *(const short8*)&As[(ra * 8 + ((kk * 4 + quad) ^ swz8(ra))) * 8];
    }
#pragma unroll
    for (int j = 0; j < 2; ++j) {
      int rb = wn * 32 + j * 16 + l16;
#pragma unroll
      for (int kk = 0; kk < 2; ++kk)
        b[j][kk] = *(const short8*)&Bs[(rb * 8 + ((kk * 4 + quad) ^ swz8(rb))) * 8];
    }
#pragma unroll
    for (int kk = 0; kk < 2; ++kk)
#pragma unroll
      for (int i = 0; i < 4; ++i)
#pragma unroll
        for (int j = 0; j < 2; ++j)
          acc[i][j] = __builtin_amdgcn_mfma_f32_16x16x32_bf16(a[i][kk], b[j][kk], acc[i][j], 0, 0, 0);
    __syncthreads();
  }

#pragma unroll
  for (int i = 0; i < 4; ++i)
#pragma unroll
    for (int j = 0; j < 2; ++j)
#pragma unroll
      for (int r = 0; r < 4; ++r) {
        size_t row = row0 + wm * 64 + i * 16 + quad * 4 + r;
        size_t col = col0 + wn * 32 + j * 16 + l16;
        C[row * 2048 + col] = acc[i][j][r];
      }
}

extern "C" void kernel_launch(void* const* d_in, const int* in_sizes, int n_in,
                              void* d_out, int out_size, void* d_ws, size_t ws_size,
                              hipStream_t stream) {
  const float* X  = (const float*)d_in[0];
  const float* wq = (const float*)d_in[1];
  const float* wk = (const float*)d_in[2];
  const float* wv = (const float*)d_in[3];
  const float* wo = (const float*)d_in[4];
  const int*  pos = (const int*)d_in[5];
  float* out = (float*)d_out;

  if (ws_size < 9 * E * sizeof(ushort_t)) return;  // need 72 MB scratch

  ushort_t* Xb  = (ushort_t*)d_ws;
  ushort_t* Wqb = Xb + E;
  ushort_t* Wkb = Xb + 2 * E;
  ushort_t* Wvb = Xb + 3 * E;
  ushort_t* Wob = Xb + 4 * E;
  ushort_t* Qm  = Xb + 5 * E;
  ushort_t* Km  = Xb + 6 * E;
  ushort_t* Vtm = Xb + 7 * E;
  ushort_t* Om  = Xb + 8 * E;

  dim3 b256(256);
  k_cvt5<<<dim3(4096, 5), b256, 0, stream>>>(X, wq, wk, wv, wo, Xb);
  k_gemm_qkv<<<dim3(16, 16, 3), b256, 0, stream>>>(Xb, Wqb, Wkb, Wvb, Qm, Km, Vtm, pos);
  k_attn<<<512, b256, 0, stream>>>(Qm, Km, Vtm, Om);
  k_gemm_wo<<<dim3(32, 16), b256, 0, stream>>>(Om, Wob, out);
}